// Round 1
// baseline (127.528 us; speedup 1.0000x reference)
//
#include <hip/hip_runtime.h>
#include <stdint.h>

// VQ-VAE vector quantizer, MI355X — fused argmin+gather+loss, 2-dispatch pipeline.
// z: (32, 256, 32, 32) fp32 ; embedding: (1024, 256) fp32
// out: [0, 8388608) quant_z (N,C,H,W) ; [8388608] vq_loss ; [8388609] commit_loss
//
//   argmin_k ||z-e_k||^2 = argmin_k ( ||e_k||^2 - 2 z.e_k )   [bf16 MFMA scores]
//   vq_loss = (sum_m (||z_m||^2 + s_min(m))) / (M*C), commit = 0.25*vq_loss
//
// vq_main: 256 blocks x 512 thr (8 waves = 2/SIMD; was 4 waves = 1/SIMD -> 9% occ).
// Gather + finalize fused into the epilogue (indices never leave LDS).

#define CDIM  256

// ws byte offsets
#define WS_EB     16777216u    // bf16[1024][256]
#define WS_ENORM  17301504u    // f32[1024]
#define WS_CNT    17436672u    // u32 completion counter (in old idx region)
#define WS_LOSS   19664896u    // f32

// LDS byte offsets (dynamic shared, 141824 total)
#define L_ZS     0u            // bf16 [128 rows][256 c], XOR-granule swizzle
#define L_ES     65536u        // bf16 [2][64 codes][256 c], swizzled, double buffer
#define L_TILEF  98304u        // f32[32][132] transpose scratch (aliases es buf1)
#define L_ENORM  131072u       // f32[1024]
#define L_ZNP    135168u       // f32[128][4]
#define L_CAND   137216u       // float2[8][64]
#define L_IDX    141312u       // i32[128]
#define LDS_TOTAL 141824

typedef __attribute__((ext_vector_type(8))) short bf16x8;
typedef __attribute__((ext_vector_type(4))) float f32x4;

__device__ inline unsigned short f2bf(float f) {
  uint32_t u = __float_as_uint(f);
  return (unsigned short)((u + 0x7FFFu + ((u >> 16) & 1u)) >> 16);
}

__device__ inline void load16(const void* g, void* l) {
  __builtin_amdgcn_global_load_lds((const __attribute__((address_space(1))) void*)g,
                                   (__attribute__((address_space(3))) void*)l, 16, 0, 0);
}

// E -> bf16 Eb + eNorm ; zero loss + counter. 256 blocks x 256 thr.
__global__ void vq_prep_e(const float* __restrict__ E, char* __restrict__ ws) {
  const int w = threadIdx.x >> 6, l = threadIdx.x & 63;
  const int row = blockIdx.x * 4 + w;
  const float4 v = *(const float4*)(E + (size_t)row * CDIM + l * 4);
  ushort4 b;
  b.x = f2bf(v.x); b.y = f2bf(v.y); b.z = f2bf(v.z); b.w = f2bf(v.w);
  *(ushort4*)(ws + WS_EB + (size_t)row * 512 + l * 8) = b;
  float s = v.x * v.x + v.y * v.y + v.z * v.z + v.w * v.w;
  #pragma unroll
  for (int m = 32; m >= 1; m >>= 1) s += __shfl_xor(s, m);
  if (l == 0) ((float*)(ws + WS_ENORM))[row] = s;
  if (blockIdx.x == 0 && threadIdx.x == 0) {
    *((float*)(ws + WS_LOSS)) = 0.f;
    *((unsigned*)(ws + WS_CNT)) = 0u;
  }
}

// One block per CU, 8 waves: 128 z-rows resident; 1024 codes streamed; argmin +
// loss + fused quant_z gather + last-block loss finalize.
__global__ __launch_bounds__(512, 2)
void vq_main(const float* __restrict__ z, const float* __restrict__ E,
             char* __restrict__ ws, float* __restrict__ out) {
  extern __shared__ char lds[];
  unsigned short* zs = (unsigned short*)(lds + L_ZS);
  char* esb          = lds + L_ES;
  float* tileF       = (float*)(lds + L_TILEF);   // aliases es buf1 (free in prologue)
  float* eNormS      = (float*)(lds + L_ENORM);
  float* znPart      = (float*)(lds + L_ZNP);
  float2* cand       = (float2*)(lds + L_CAND);
  int* idxS          = (int*)(lds + L_IDX);
  float* tileG       = (float*)(lds + L_ZS);      // epilogue gather tile [256][132]

  const int t = threadIdx.x, w = t >> 6, l = t & 63;
  const int mt = blockIdx.x;                 // 0..255
  const int n = mt >> 3, hw0 = (mt & 7) << 7;
  const char* Eb = ws + WS_EB;

  // per-thread staging source offsets for one es tile (swizzle baked in)
  int srcOff[4];
  #pragma unroll
  for (int i = 0; i < 4; ++i) {
    const int j = (i * 8 + w) * 64 + l;      // LDS granule 0..2047
    const int q = j >> 5;                    // code-in-tile 0..63
    const int g = (j & 31) ^ (q & 7);        // source granule (un-swizzle)
    srcOff[i] = q * 512 + g * 16;
  }
  // stage es tile 0 into buf 0 ; preload eNorm into LDS
  #pragma unroll
  for (int i = 0; i < 4; ++i)
    load16(Eb + srcOff[i], esb + (i * 8 + w) * 1024);
  if (w < 4)
    load16((const char*)(ws + WS_ENORM) + (w * 64 + l) * 16, (char*)eNormS + w * 1024);

  // ---- prologue: z (c-major) -> zs (row-major bf16, swizzled) + |z|^2 ----
  const float* zb0 = z + (size_t)n * (CDIM * 1024) + hw0;
  const int cA = t >> 4;                     // c within 32-chunk (0..31)
  const int hA = (t & 15) * 8;               // hw offset (2 float4)
  const int r2 = (t >> 1) & 127, gsub = t & 1, ksel = t >> 8;
  const int cbase = gsub * 16 + ksel * 8;    // 8 consecutive c per thread
  float4 v0 = *(const float4*)(zb0 + (size_t)cA * 1024 + hA);
  float4 v1 = *(const float4*)(zb0 + (size_t)cA * 1024 + hA + 4);
  float znAcc = 0.f;
  for (int ci = 0; ci < 8; ++ci) {
    __syncthreads();                         // tileF free
    *(float4*)(tileF + cA * 132 + hA)     = v0;
    *(float4*)(tileF + cA * 132 + hA + 4) = v1;
    if (ci < 7) {
      const float* src = zb0 + (size_t)((ci + 1) * 32 + cA) * 1024 + hA;
      v0 = *(const float4*)(src);
      v1 = *(const float4*)(src + 4);
    }
    __syncthreads();                         // tileF ready
    union { bf16x8 v; unsigned short u[8]; } pk;
    #pragma unroll
    for (int k = 0; k < 8; ++k) {
      const float sv = tileF[(cbase + k) * 132 + r2];
      znAcc += sv * sv;
      pk.u[k] = f2bf(sv);
    }
    const int g  = ci * 4 + gsub * 2 + ksel; // logical granule 0..31
    const int gp = g ^ (r2 & 7);
    *(bf16x8*)((char*)zs + r2 * 512 + gp * 16) = pk.v;
  }
  znPart[r2 * 4 + gsub * 2 + ksel] = znAcc;
  __syncthreads();                           // zs complete (also drains tile-0 + eNorm staging)

  // ---- cache A fragments in registers: 64 rows x K=256 per wave ----
  const int wrow = (w & 1) * 64, chalf = (w >> 1) * 16;
  const int lrow = l & 15, lk = l >> 4;
  bf16x8 af[4][8];
  #pragma unroll
  for (int rs = 0; rs < 4; ++rs) {
    const int r = wrow + rs * 16 + lrow;
    #pragma unroll
    for (int kg = 0; kg < 8; ++kg) {
      const int gp = (kg * 4 + lk) ^ (r & 7);
      af[rs][kg] = *(const bf16x8*)((const char*)zs + r * 512 + gp * 16);
    }
  }

  // ---- main loop: 16 tiles x 64 codes, es double-buffered ----
  float bb[4][4]; int bidx[4][4];
  #pragma unroll
  for (int rs = 0; rs < 4; ++rs)
    #pragma unroll
    for (int i = 0; i < 4; ++i) { bb[rs][i] = 3.4e38f; bidx[rs][i] = 0; }

  const int qcode = chalf + lrow;            // code-in-tile for this lane
  for (int tile = 0; tile < 16; ++tile) {
    const int cur = tile & 1;
    if (tile < 15) {                         // stage next tile
      const char* src = Eb + (size_t)(tile + 1) * 32768;
      char* dst = esb + (cur ^ 1) * 32768;
      #pragma unroll
      for (int i = 0; i < 4; ++i)
        load16(src + srcOff[i], dst + (i * 8 + w) * 1024);
    }
    f32x4 acc[4];
    #pragma unroll
    for (int rs = 0; rs < 4; ++rs) acc[rs] = (f32x4){0.f, 0.f, 0.f, 0.f};
    const char* ebase = (const char*)esb + cur * 32768 + qcode * 512;
    #pragma unroll
    for (int kg = 0; kg < 8; ++kg) {
      const int gp = (kg * 4 + lk) ^ (qcode & 7);
      const bf16x8 bf = *(const bf16x8*)(ebase + gp * 16);
      #pragma unroll
      for (int rs = 0; rs < 4; ++rs)
        acc[rs] = __builtin_amdgcn_mfma_f32_16x16x32_bf16(af[rs][kg], bf, acc[rs], 0, 0, 0);
    }
    // fold scores into running argmin (codes ascending; strict < keeps first index)
    const int code = tile * 64 + qcode;
    const float eN = eNormS[code];
    #pragma unroll
    for (int rs = 0; rs < 4; ++rs)
      #pragma unroll
      for (int i = 0; i < 4; ++i) {
        const float s = fmaf(-2.f, acc[rs][i], eN);
        if (s < bb[rs][i]) { bb[rs][i] = s; bidx[rs][i] = code; }
      }
    __syncthreads();                         // es[cur] consumed; next staging drained
  }

  // ---- reduce over 16 code-lanes, cross-wave combine, loss ----
  #pragma unroll
  for (int rs = 0; rs < 4; ++rs)
    #pragma unroll
    for (int i = 0; i < 4; ++i)
      #pragma unroll
      for (int m = 8; m >= 1; m >>= 1) {
        const float ob = __shfl_xor(bb[rs][i], m);
        const int   oi = __shfl_xor(bidx[rs][i], m);
        if (ob < bb[rs][i] || (ob == bb[rs][i] && oi < bidx[rs][i])) { bb[rs][i] = ob; bidx[rs][i] = oi; }
      }
  if (lrow == 0) {
    #pragma unroll
    for (int rs = 0; rs < 4; ++rs)
      #pragma unroll
      for (int i = 0; i < 4; ++i) {
        float2 c2; c2.x = bb[rs][i]; c2.y = __int_as_float(bidx[rs][i]);
        cand[w * 64 + rs * 16 + lk * 4 + i] = c2;
      }
  }
  __syncthreads();
  if (t < 128) {
    const int r = t;
    float best = 3.4e38f; int bi = 0x7fffffff;
    #pragma unroll
    for (int cg = 0; cg < 4; ++cg) {        // 4 code-groups, ascending
      const float2 c2 = cand[(cg * 2 + (r >> 6)) * 64 + (r & 63)];
      const int ci2 = __float_as_int(c2.y);
      if (c2.x < best || (c2.x == best && ci2 < bi)) { best = c2.x; bi = ci2; }
    }
    idxS[r] = bi;
    float d = znPart[r * 4] + znPart[r * 4 + 1] + znPart[r * 4 + 2] + znPart[r * 4 + 3] + best;
    #pragma unroll
    for (int m = 32; m >= 1; m >>= 1) d += __shfl_xor(d, m);
    if ((t & 63) == 0) atomicAdd((float*)(ws + WS_LOSS), d);
  }
  __syncthreads();                           // idxS ready; loss adds drained

  // ---- fused gather: quant_z = E[idx] transposed to (c, hw) ----
  // tileG f32[256 c][132] aliases zs+es (dead). idxS (141312+) untouched.
  const int rIdx = t >> 2, qg = t & 3;
  const int grow = idxS[rIdx];
  const float4* erow = (const float4*)(E + (size_t)grow * CDIM);
  #pragma unroll
  for (int j = 0; j < 16; ++j) {
    const float4 v = erow[qg + j * 4];
    const int c0 = (qg + j * 4) * 4;
    tileG[(c0 + 0) * 132 + rIdx] = v.x;
    tileG[(c0 + 1) * 132 + rIdx] = v.y;
    tileG[(c0 + 2) * 132 + rIdx] = v.z;
    tileG[(c0 + 3) * 132 + rIdx] = v.w;
  }
  __syncthreads();
  float* obase = out + (size_t)n * (CDIM * 1024) + hw0;
  const int rq = (t & 3) * 4;
  #pragma unroll
  for (int csel = 0; csel < 2; ++csel) {
    const int c = csel * 128 + (t >> 2);
    #pragma unroll
    for (int k = 0; k < 8; ++k)
      *(float4*)(obase + (size_t)c * 1024 + rq + k * 16) =
        *(const float4*)(tileG + c * 132 + rq + k * 16);
  }

  // ---- last-block loss finalize (replaces vq_finalize dispatch) ----
  if (t == 0) {
    __threadfence();
    const unsigned done = atomicAdd((unsigned*)(ws + WS_CNT), 1u);
    if (done == 255u) {
      const float L = atomicAdd((float*)(ws + WS_LOSS), 0.0f) * (1.0f / 8388608.0f);
      out[8388608] = L;
      out[8388609] = 0.25f * L;
    }
  }
}

extern "C" void kernel_launch(void* const* d_in, const int* in_sizes, int n_in,
                              void* d_out, int out_size, void* d_ws, size_t ws_size,
                              hipStream_t stream) {
  const float* z = (const float*)d_in[0];
  const float* E = (const float*)d_in[1];
  float* out = (float*)d_out;
  char*  ws  = (char*)d_ws;

  static const int kLds = LDS_TOTAL;
  (void)hipFuncSetAttribute((const void*)vq_main,
                            hipFuncAttributeMaxDynamicSharedMemorySize, kLds);

  vq_prep_e <<<256, 256, 0, stream>>>(E, ws);
  vq_main   <<<256, 512, kLds, stream>>>(z, E, ws, out);
}